// Round 1
// baseline (489.776 us; speedup 1.0000x reference)
//
#include <hip/hip_runtime.h>
#include <hip/hip_bf16.h>

// DeformableTransformer (Deformable-DETR MSDeformAttn), f32 reference-exact path.
// Q=19947, D_MODEL=256, M=8 heads, L=4 levels, P=4 points, DH=32.
// SPATIAL = [(100,150),(50,75),(25,38),(13,19)], starts = {0,15000,18750,19700}.

#define M_HEADS 8
#define DH_ 32
#define DMODEL 256

// ---------------------------------------------------------------------------
// Generic GEMM:  C[Q x NCOLS] = A[Q x 256] @ W[256 x NCOLS] + b
// 16 rows per block staged in LDS; one thread per output column.
// Each W element loaded once per block feeds 16 FMAs -> W traffic stays in L2.
// Optional row mask (padding mask) zeroes output rows.
// ---------------------------------------------------------------------------
template <int NCOLS>
__global__ __launch_bounds__(NCOLS) void gemm_bias_k256(
    const float* __restrict__ A, const float* __restrict__ W,
    const float* __restrict__ b, float* __restrict__ C, int Q,
    const unsigned char* __restrict__ mask)
{
    constexpr int ROWS = 16;
    __shared__ float As[ROWS][256];

    const int q0 = blockIdx.x * ROWS;
    const int col = threadIdx.x;

    // Stage A tile (16 x 256 f32 = 16 KiB) with float4 loads.
    float4* Asv = (float4*)&As[0][0];
    const int nvec = ROWS * 64;  // 1024 float4
    for (int i = threadIdx.x; i < nvec; i += NCOLS) {
        int r = i >> 6;
        int c4 = i & 63;
        int rr = q0 + r;
        if (rr >= Q) rr = Q - 1;  // clamp: dup row, never stored
        Asv[i] = ((const float4*)(A + (size_t)rr * 256))[c4];
    }
    __syncthreads();

    float acc[ROWS];
#pragma unroll
    for (int r = 0; r < ROWS; ++r) acc[r] = 0.f;

#pragma unroll 4
    for (int k = 0; k < 256; ++k) {
        float w = W[(size_t)k * NCOLS + col];  // coalesced across lanes
#pragma unroll
        for (int r = 0; r < ROWS; ++r) acc[r] += As[r][k] * w;  // LDS broadcast
    }

    const float bias = b[col];
#pragma unroll
    for (int r = 0; r < ROWS; ++r) {
        int rr = q0 + r;
        if (rr < Q) {
            float v = acc[r] + bias;
            if (mask && mask[rr]) v = 0.f;
            C[(size_t)rr * NCOLS + col] = v;
        }
    }
}

// ---------------------------------------------------------------------------
// Softmax over 16 contiguous logits per (q, m), in place.
// ---------------------------------------------------------------------------
__global__ __launch_bounds__(256) void softmax16_k(float* __restrict__ aw, int QM)
{
    int g = blockIdx.x * 256 + threadIdx.x;
    if (g >= QM) return;
    float* p = aw + (size_t)g * 16;
    float v[16];
    float mx = -1e30f;
#pragma unroll
    for (int i = 0; i < 16; ++i) { v[i] = p[i]; mx = fmaxf(mx, v[i]); }
    float s = 0.f;
#pragma unroll
    for (int i = 0; i < 16; ++i) { v[i] = __expf(v[i] - mx); s += v[i]; }
    float inv = 1.f / s;
#pragma unroll
    for (int i = 0; i < 16; ++i) p[i] = v[i] * inv;
}

// ---------------------------------------------------------------------------
// Bilinear sampling + attention-weighted accumulation.
// One 32-lane subgroup per (q, m); lane == dh channel. 8 subgroups / block.
// value layout: [q][m][dh] flat (q*256 + m*32 + dh), per-level row-major HxW.
// ---------------------------------------------------------------------------
__global__ __launch_bounds__(256) void sample_k(
    const float* __restrict__ value, const float* __restrict__ off,
    const float* __restrict__ aw, const float* __restrict__ ref,
    float* __restrict__ out2, int Q)
{
    const int   Hs[4]  = {100, 50, 25, 13};
    const int   Ws[4]  = {150, 75, 38, 19};
    const int   st[4]  = {0, 15000, 18750, 19700};

    const int g = blockIdx.x * 8 + (threadIdx.x >> 5);
    const int lane = threadIdx.x & 31;
    if (g >= Q * M_HEADS) return;
    const int q = g >> 3;
    const int m = g & 7;

    const float* offq = off + (size_t)q * 256 + m * 32;   // [l][p][2]
    const float* awq  = aw  + (size_t)q * 128 + m * 16;   // [l*4+p]
    const float* vbase = value + (size_t)m * 32 + lane;

    float acc = 0.f;
#pragma unroll
    for (int l = 0; l < 4; ++l) {
        const float rx = ref[(size_t)q * 8 + l * 2 + 0];
        const float ry = ref[(size_t)q * 8 + l * 2 + 1];
        const int Wc = Ws[l], Hc = Hs[l], s0 = st[l];
        const float fw = (float)Wc, fh = (float)Hc;
#pragma unroll
        for (int p = 0; p < 4; ++p) {
            const float ox = offq[l * 8 + p * 2 + 0];
            const float oy = offq[l * 8 + p * 2 + 1];
            float gx = 2.f * (rx + ox / fw) - 1.f;
            float gy = 2.f * (ry + oy / fh) - 1.f;
            gx = fminf(fmaxf(gx, -2.f), 2.f);
            gy = fminf(fmaxf(gy, -2.f), 2.f);
            const float x = (gx + 1.f) * (fw * 0.5f) - 0.5f;
            const float y = (gy + 1.f) * (fh * 0.5f) - 0.5f;
            const float x0f = floorf(x), y0f = floorf(y);
            const int x0 = (int)x0f, y0 = (int)y0f;
            const float wx1 = x - x0f, wx0 = 1.f - wx1;
            const float wy1 = y - y0f, wy0 = 1.f - wy1;
            const float a = awq[l * 4 + p];

            float s = 0.f;
#pragma unroll
            for (int cy = 0; cy < 2; ++cy) {
#pragma unroll
                for (int cx = 0; cx < 2; ++cx) {
                    const int xi = x0 + cx, yi = y0 + cy;
                    const bool valid = (xi >= 0) & (xi < Wc) & (yi >= 0) & (yi < Hc);
                    const int xc = min(max(xi, 0), Wc - 1);
                    const int yc = min(max(yi, 0), Hc - 1);
                    const float wgt = (cx ? wx1 : wx0) * (cy ? wy1 : wy0);
                    const float v = vbase[(size_t)(s0 + yc * Wc + xc) * 256];
                    s += valid ? wgt * v : 0.f;
                }
            }
            acc += a * s;
        }
    }
    out2[(size_t)q * 256 + m * 32 + lane] = acc;
}

// ---------------------------------------------------------------------------
extern "C" void kernel_launch(void* const* d_in, const int* in_sizes, int n_in,
                              void* d_out, int out_size, void* d_ws, size_t ws_size,
                              hipStream_t stream)
{
    const float* query = (const float*)d_in[0];                 // (Q, 256)
    const float* refpt = (const float*)d_in[1];                 // (Q, 4, 2)
    const float* inflat = (const float*)d_in[2];                // (Q, 256)
    const unsigned char* mask = (const unsigned char*)d_in[3];  // (Q,) all-false
    const float* W_off = (const float*)d_in[4];                 // (256, 256)
    const float* b_off = (const float*)d_in[5];                 // (256,)
    const float* W_attn = (const float*)d_in[6];                // (256, 128)
    const float* b_attn = (const float*)d_in[7];                // (128,)
    const float* W_val = (const float*)d_in[8];                 // (256, 256)
    const float* b_val = (const float*)d_in[9];                 // (256,)
    const float* W_out = (const float*)d_in[10];                // (256, 256)
    const float* b_out = (const float*)d_in[11];                // (256,)
    float* out = (float*)d_out;

    const int Q = in_sizes[0] / DMODEL;  // 19947

    // Workspace layout (f32): value Q*256 | off Q*256 | aw Q*128 | out2 Q*256
    float* value = (float*)d_ws;
    float* off   = value + (size_t)Q * 256;
    float* aw    = off   + (size_t)Q * 256;
    float* out2  = aw    + (size_t)Q * 128;

    const int gblk = (Q + 15) / 16;

    // 1) value = inflat @ W_val + b_val  (masked)
    gemm_bias_k256<256><<<gblk, 256, 0, stream>>>(inflat, W_val, b_val, value, Q, mask);
    // 2) off = query @ W_off + b_off
    gemm_bias_k256<256><<<gblk, 256, 0, stream>>>(query, W_off, b_off, off, Q, nullptr);
    // 3) attn logits = query @ W_attn + b_attn
    gemm_bias_k256<128><<<gblk, 128, 0, stream>>>(query, W_attn, b_attn, aw, Q, nullptr);
    // 4) softmax over 16 per (q, m)
    const int QM = Q * M_HEADS;
    softmax16_k<<<(QM + 255) / 256, 256, 0, stream>>>(aw, QM);
    // 5) bilinear sample + weighted accumulate -> out2
    sample_k<<<Q, 256, 0, stream>>>(value, off, aw, refpt, out2, Q);
    // 6) out = out2 @ W_out + b_out
    gemm_bias_k256<256><<<gblk, 256, 0, stream>>>(out2, W_out, b_out, out, Q, nullptr);
}

// Round 2
// 301.346 us; speedup vs baseline: 1.6253x; 1.6253x over previous
//
#include <hip/hip_runtime.h>
#include <hip/hip_bf16.h>

// Deformable-DETR MSDeformAttn, fp32. Q=19947, D=256, M=8, L=4, P=4, DH=32.
// SPATIAL = [(100,150),(50,75),(25,38),(13,19)], starts = {0,15000,18750,19700}.

#define DMODEL 256

// ---------------------------------------------------------------------------
// Tiled GEMM: C[Q x NC] = A[Q x 256] @ W[256 x NC] + b, optional row mask.
// 64x64 tile per 256-thread block, 4x4 micro-tile per thread.
// A staged transposed As[k][r] (pad 68 -> conflict-free), W staged Ws[k][c].
// ---------------------------------------------------------------------------
template <int NC>
__global__ __launch_bounds__(256, 4) void gemm_tile_k(
    const float* __restrict__ A, const float* __restrict__ W,
    const float* __restrict__ b, float* __restrict__ C, int Q,
    const unsigned char* __restrict__ mask)
{
    __shared__ float As[16][68];
    __shared__ float Ws[16][68];

    const int t = threadIdx.x;
    const int tx = t & 15, ty = t >> 4;      // 16 x 16 threads
    const int r0 = blockIdx.x * 64;
    const int c0 = blockIdx.y * 64;

    float acc[4][4];
#pragma unroll
    for (int i = 0; i < 4; ++i)
#pragma unroll
        for (int j = 0; j < 4; ++j) acc[i][j] = 0.f;

    // staging assignments
    const int a_r = t >> 2;            // 0..63 row within tile
    const int a_kh = (t & 3) * 4;      // k chunk of 4
    const int w_k = t >> 4;            // 0..15 k within tile
    const int w_c = (t & 15) * 4;      // col chunk of 4

    int ar = r0 + a_r;
    if (ar >= Q) ar = Q - 1;           // clamp (dup row, never stored)
    const float* Arow = A + (size_t)ar * 256;

    for (int k0 = 0; k0 < 256; k0 += 16) {
        const float4 av = *(const float4*)(Arow + k0 + a_kh);
        const float4 wv = *(const float4*)(W + (size_t)(k0 + w_k) * NC + c0 + w_c);
        __syncthreads();   // protect LDS from previous iteration's readers
        As[a_kh + 0][a_r] = av.x;
        As[a_kh + 1][a_r] = av.y;
        As[a_kh + 2][a_r] = av.z;
        As[a_kh + 3][a_r] = av.w;
        *(float4*)&Ws[w_k][w_c] = wv;
        __syncthreads();
#pragma unroll
        for (int kk = 0; kk < 16; ++kk) {
            const float4 a4 = *(const float4*)&As[kk][ty * 4];
            const float4 w4 = *(const float4*)&Ws[kk][tx * 4];
            const float aa[4] = {a4.x, a4.y, a4.z, a4.w};
            const float ww[4] = {w4.x, w4.y, w4.z, w4.w};
#pragma unroll
            for (int i = 0; i < 4; ++i)
#pragma unroll
                for (int j = 0; j < 4; ++j) acc[i][j] += aa[i] * ww[j];
        }
    }

    const float4 bv = *(const float4*)(b + c0 + tx * 4);
    const float bb[4] = {bv.x, bv.y, bv.z, bv.w};
#pragma unroll
    for (int i = 0; i < 4; ++i) {
        const int rr = r0 + ty * 4 + i;
        if (rr < Q) {
            const bool z = (mask != nullptr) && mask[rr];
            float4 o;
            o.x = z ? 0.f : acc[i][0] + bb[0];
            o.y = z ? 0.f : acc[i][1] + bb[1];
            o.z = z ? 0.f : acc[i][2] + bb[2];
            o.w = z ? 0.f : acc[i][3] + bb[3];
            *(float4*)(C + (size_t)rr * NC + c0 + tx * 4) = o;
        }
    }
}

// ---------------------------------------------------------------------------
// Fused softmax + bilinear sampling + weighted accumulation.
// One 64-lane wave per (q, m); 4 waves per block.
// Phase 1: lane = point*4 + corner -> compute (flat idx, combined weight),
//          softmax over 16 points via xor-shuffles; stash in LDS (512B/wave).
// Phase 2: lane = corner_group*8 + channel_quad -> gather float4 + FMA,
//          butterfly-reduce over corner groups, 8 lanes store float4.
// ---------------------------------------------------------------------------
__global__ __launch_bounds__(256) void msda_k(
    const float* __restrict__ value, const float* __restrict__ off,
    const float* __restrict__ logits, const float* __restrict__ ref,
    float* __restrict__ out2, int Q)
{
    __shared__ int   sIdx[4][64];
    __shared__ float sWt[4][64];

    const int t = threadIdx.x;
    const int w = t >> 6;
    const int lane = t & 63;
    const int g = blockIdx.x * 4 + w;        // Q*8 divisible by 4
    const int q = g >> 3, m = g & 7;

    // ---- phase 1: one corner per lane ----
    {
        const int p = lane >> 2;             // point 0..15
        const int c = lane & 3;              // corner 0..3
        const int l = p >> 2;                // level 0..3

        // softmax over the 16 points (values replicated 4x across corners)
        float logit = logits[(size_t)q * 128 + m * 16 + p];
        float mx = logit;
#pragma unroll
        for (int s = 4; s < 64; s <<= 1) mx = fmaxf(mx, __shfl_xor(mx, s, 64));
        const float e = __expf(logit - mx);
        float sum = e;
#pragma unroll
        for (int s = 4; s < 64; s <<= 1) sum += __shfl_xor(sum, s, 64);
        const float a = e / sum;

        const float ox = off[(size_t)q * 256 + m * 32 + p * 2 + 0];
        const float oy = off[(size_t)q * 256 + m * 32 + p * 2 + 1];
        const float rx = ref[(size_t)q * 8 + l * 2 + 0];
        const float ry = ref[(size_t)q * 8 + l * 2 + 1];

        const int Wc = (l == 0) ? 150 : (l == 1) ? 75 : (l == 2) ? 38 : 19;
        const int Hc = (l == 0) ? 100 : (l == 1) ? 50 : (l == 2) ? 25 : 13;
        const int s0 = (l == 0) ? 0 : (l == 1) ? 15000 : (l == 2) ? 18750 : 19700;
        const float fw = (float)Wc, fh = (float)Hc;

        float gx = 2.f * (rx + ox / fw) - 1.f;
        float gy = 2.f * (ry + oy / fh) - 1.f;
        gx = fminf(fmaxf(gx, -2.f), 2.f);
        gy = fminf(fmaxf(gy, -2.f), 2.f);
        const float x = (gx + 1.f) * (fw * 0.5f) - 0.5f;
        const float y = (gy + 1.f) * (fh * 0.5f) - 0.5f;
        const float x0f = floorf(x), y0f = floorf(y);
        const int x0 = (int)x0f, y0 = (int)y0f;
        const float wx1 = x - x0f, wy1 = y - y0f;

        const int cx = c & 1, cy = c >> 1;
        const int xi = x0 + cx, yi = y0 + cy;
        const float wx = cx ? wx1 : 1.f - wx1;
        const float wy = cy ? wy1 : 1.f - wy1;
        const bool valid = (xi >= 0) & (xi < Wc) & (yi >= 0) & (yi < Hc);
        const int xc = min(max(xi, 0), Wc - 1);
        const int yc = min(max(yi, 0), Hc - 1);

        sIdx[w][lane] = (s0 + yc * Wc + xc) * 256 + m * 32;
        sWt[w][lane] = valid ? a * wx * wy : 0.f;
    }
    __syncthreads();

    // ---- phase 2: gather + accumulate ----
    const int cg = lane >> 3;                // corner group 0..7
    const int ch = (lane & 7) * 4;           // channel quad base
    const float* vb = value + ch;

    float4 acc = {0.f, 0.f, 0.f, 0.f};
#pragma unroll
    for (int i = 0; i < 8; ++i) {
        const int k = i * 8 + cg;
        const float wt = sWt[w][k];          // 8-way broadcast, conflict-free
        const int idx = sIdx[w][k];
        const float4 v = *(const float4*)(vb + idx);
        acc.x += wt * v.x;
        acc.y += wt * v.y;
        acc.z += wt * v.z;
        acc.w += wt * v.w;
    }
#pragma unroll
    for (int s = 8; s < 64; s <<= 1) {
        acc.x += __shfl_xor(acc.x, s, 64);
        acc.y += __shfl_xor(acc.y, s, 64);
        acc.z += __shfl_xor(acc.z, s, 64);
        acc.w += __shfl_xor(acc.w, s, 64);
    }
    if (lane < 8)
        *(float4*)(out2 + (size_t)q * 256 + m * 32 + lane * 4) = acc;
}

// ---------------------------------------------------------------------------
extern "C" void kernel_launch(void* const* d_in, const int* in_sizes, int n_in,
                              void* d_out, int out_size, void* d_ws, size_t ws_size,
                              hipStream_t stream)
{
    const float* query = (const float*)d_in[0];                 // (Q, 256)
    const float* refpt = (const float*)d_in[1];                 // (Q, 4, 2)
    const float* inflat = (const float*)d_in[2];                // (Q, 256)
    const unsigned char* mask = (const unsigned char*)d_in[3];  // (Q,)
    const float* W_off = (const float*)d_in[4];                 // (256, 256)
    const float* b_off = (const float*)d_in[5];                 // (256,)
    const float* W_attn = (const float*)d_in[6];                // (256, 128)
    const float* b_attn = (const float*)d_in[7];                // (128,)
    const float* W_val = (const float*)d_in[8];                 // (256, 256)
    const float* b_val = (const float*)d_in[9];                 // (256,)
    const float* W_out = (const float*)d_in[10];                // (256, 256)
    const float* b_out = (const float*)d_in[11];                // (256,)
    float* out = (float*)d_out;

    const int Q = in_sizes[0] / DMODEL;  // 19947

    // Workspace (f32): value Q*256 | off Q*256 | logits Q*128 | out2 Q*256
    float* value = (float*)d_ws;
    float* off   = value + (size_t)Q * 256;
    float* aw    = off   + (size_t)Q * 256;
    float* out2  = aw    + (size_t)Q * 128;

    const int rb = (Q + 63) / 64;
    dim3 g256(rb, 4);   // 64-col tiles x 4 = 256 cols
    dim3 g128(rb, 2);   // 128 cols

    // 1) value = inflat @ W_val + b_val (masked)
    gemm_tile_k<256><<<g256, 256, 0, stream>>>(inflat, W_val, b_val, value, Q, mask);
    // 2) off = query @ W_off + b_off
    gemm_tile_k<256><<<g256, 256, 0, stream>>>(query, W_off, b_off, off, Q, nullptr);
    // 3) logits = query @ W_attn + b_attn
    gemm_tile_k<128><<<g128, 256, 0, stream>>>(query, W_attn, b_attn, aw, Q, nullptr);
    // 4) fused softmax + sample + accumulate -> out2
    msda_k<<<(Q * 8) / 4, 256, 0, stream>>>(value, off, aw, refpt, out2, Q);
    // 5) out = out2 @ W_out + b_out
    gemm_tile_k<256><<<g256, 256, 0, stream>>>(out2, W_out, b_out, out, Q, nullptr);
}

// Round 3
// 250.575 us; speedup vs baseline: 1.9546x; 1.2026x over previous
//
#include <hip/hip_runtime.h>
#include <hip/hip_bf16.h>

// Deformable-DETR MSDeformAttn, Q=19947, D=256, M=8, L=4, P=4, DH=32.
// GEMMs on bf16 MFMA (hi/lo split for the final out-proj); sampling fused fp32.

#define DMODEL 256

typedef __attribute__((ext_vector_type(8))) short bf16x8;
typedef __attribute__((ext_vector_type(4))) float f32x4;

static __device__ inline unsigned short f2bf(float f) {
    unsigned int u = __builtin_bit_cast(unsigned int, f);
    u = (u + 0x7fffu + ((u >> 16) & 1u)) >> 16;   // RNE (finite inputs)
    return (unsigned short)u;
}
static __device__ inline float bf2f(unsigned short h) {
    return __builtin_bit_cast(float, (unsigned int)h << 16);
}

// ---------------------------------------------------------------------------
// W[k][c] fp32  ->  Wt[c][k] bf16 (and optional lo-residual).  K = 256.
// grid: (K/64, NC/64), 256 threads. LDS tile transpose, coalesced both sides.
// ---------------------------------------------------------------------------
__global__ __launch_bounds__(256) void wtrans_k(
    const float* __restrict__ W, unsigned short* __restrict__ H,
    unsigned short* __restrict__ L, int NC)
{
    __shared__ unsigned short tH[64][68];
    __shared__ unsigned short tL[64][68];
    const int t = threadIdx.x;
    const int k0 = blockIdx.x * 64, c0 = blockIdx.y * 64;
    const int cl = t & 63;
#pragma unroll
    for (int i = 0; i < 16; ++i) {
        const int kl = (t >> 6) * 16 + i;
        const float v = W[(size_t)(k0 + kl) * NC + c0 + cl];
        const unsigned short h = f2bf(v);
        tH[cl][kl] = h;
        if (L) tL[cl][kl] = f2bf(v - bf2f(h));
    }
    __syncthreads();
    const int kl = t & 63;
#pragma unroll
    for (int i = 0; i < 16; ++i) {
        const int cl2 = (t >> 6) * 16 + i;
        H[(size_t)(c0 + cl2) * 256 + k0 + kl] = tH[cl2][kl];
        if (L) L[(size_t)(c0 + cl2) * 256 + k0 + kl] = tL[cl2][kl];
    }
}

// ---------------------------------------------------------------------------
// MFMA GEMM: C[Q x NC] = A[Q x 256] @ B[256 x NC] + bias, optional row mask.
// B given pre-transposed bf16 Bt[c][k] (+ lo residual when SPLIT).
// 64x64 tile / 256 threads; each wave owns a 32x32 quadrant = 2x2 tiles of
// mfma_f32_16x16x32_bf16. K staged in 64-chunks; A converted fp32->bf16
// in-kernel (hi/lo when SPLIT). SPLIT: D = Ah*Bh + Al*Bh + Ah*Bl.
// ---------------------------------------------------------------------------
template <int NC, bool SPLIT>
__global__ __launch_bounds__(256) void gemm_mfma_k(
    const float* __restrict__ A, const unsigned short* __restrict__ BtH,
    const unsigned short* __restrict__ BtL, const float* __restrict__ bias,
    float* __restrict__ C, int Q, const unsigned char* __restrict__ mask)
{
    constexpr int NS = SPLIT ? 2 : 1;
    __shared__ unsigned short As[NS][64][72];   // [r][k], pad->144B stride
    __shared__ unsigned short Bs[NS][64][72];   // [c][k]

    const int t = threadIdx.x;
    const int w = t >> 6, lane = t & 63;
    const int lr = lane & 15, quad = lane >> 4;
    const int rwl = (w & 1) * 32, cwl = (w >> 1) * 32;
    const int r0 = blockIdx.x * 64, c0 = blockIdx.y * 64;

    // staging coords: thread handles (row sr, k-quad sq*? ) chunks
    const int sr = t >> 2;
    const int sq = t & 3;

    int ar = r0 + sr; if (ar >= Q) ar = Q - 1;   // clamp: dup row, never stored
    const float* Arow = A + (size_t)ar * 256;
    const unsigned short* BrowH = BtH + (size_t)(c0 + sr) * 256;
    const unsigned short* BrowL = SPLIT ? (BtL + (size_t)(c0 + sr) * 256) : (const unsigned short*)0;

    f32x4 acc[2][2];
#pragma unroll
    for (int i = 0; i < 2; ++i)
#pragma unroll
        for (int j = 0; j < 2; ++j) acc[i][j] = (f32x4){0.f, 0.f, 0.f, 0.f};

    for (int ch = 0; ch < 4; ++ch) {
        const int kc = ch * 64;

        // global loads first (overlap other waves' compute)
        float4 av[4];
#pragma unroll
        for (int j = 0; j < 4; ++j)
            av[j] = *(const float4*)(Arow + kc + j * 16 + sq * 4);
        bf16x8 bvH[2], bvL[2];
#pragma unroll
        for (int h = 0; h < 2; ++h)
            bvH[h] = *(const bf16x8*)(BrowH + kc + sq * 16 + h * 8);
        if (SPLIT) {
#pragma unroll
            for (int h = 0; h < 2; ++h)
                bvL[h] = *(const bf16x8*)(BrowL + kc + sq * 16 + h * 8);
        }

        if (ch) __syncthreads();   // previous chunk's readers done

#pragma unroll
        for (int j = 0; j < 4; ++j) {
            const float4 v = av[j];
            ushort4 hv;
            hv.x = f2bf(v.x); hv.y = f2bf(v.y); hv.z = f2bf(v.z); hv.w = f2bf(v.w);
            *(ushort4*)&As[0][sr][j * 16 + sq * 4] = hv;
            if (SPLIT) {
                ushort4 lv;
                lv.x = f2bf(v.x - bf2f(hv.x));
                lv.y = f2bf(v.y - bf2f(hv.y));
                lv.z = f2bf(v.z - bf2f(hv.z));
                lv.w = f2bf(v.w - bf2f(hv.w));
                *(ushort4*)&As[1][sr][j * 16 + sq * 4] = lv;
            }
        }
#pragma unroll
        for (int h = 0; h < 2; ++h)
            *(bf16x8*)&Bs[0][sr][sq * 16 + h * 8] = bvH[h];
        if (SPLIT) {
#pragma unroll
            for (int h = 0; h < 2; ++h)
                *(bf16x8*)&Bs[1][sr][sq * 16 + h * 8] = bvL[h];
        }
        __syncthreads();

#pragma unroll
        for (int ks = 0; ks < 2; ++ks) {
            const int kb = ks * 32 + quad * 8;
            bf16x8 ah[2], bh[2], al[2], bl[2];
#pragma unroll
            for (int rt = 0; rt < 2; ++rt)
                ah[rt] = *(const bf16x8*)&As[0][rwl + rt * 16 + lr][kb];
#pragma unroll
            for (int ct = 0; ct < 2; ++ct)
                bh[ct] = *(const bf16x8*)&Bs[0][cwl + ct * 16 + lr][kb];
            if (SPLIT) {
#pragma unroll
                for (int rt = 0; rt < 2; ++rt)
                    al[rt] = *(const bf16x8*)&As[1][rwl + rt * 16 + lr][kb];
#pragma unroll
                for (int ct = 0; ct < 2; ++ct)
                    bl[ct] = *(const bf16x8*)&Bs[1][cwl + ct * 16 + lr][kb];
            }
#pragma unroll
            for (int rt = 0; rt < 2; ++rt)
#pragma unroll
                for (int ct = 0; ct < 2; ++ct) {
                    acc[rt][ct] = __builtin_amdgcn_mfma_f32_16x16x32_bf16(
                        ah[rt], bh[ct], acc[rt][ct], 0, 0, 0);
                    if (SPLIT) {
                        acc[rt][ct] = __builtin_amdgcn_mfma_f32_16x16x32_bf16(
                            al[rt], bh[ct], acc[rt][ct], 0, 0, 0);
                        acc[rt][ct] = __builtin_amdgcn_mfma_f32_16x16x32_bf16(
                            ah[rt], bl[ct], acc[rt][ct], 0, 0, 0);
                    }
                }
        }
    }

    // epilogue: C/D layout col=lane&15, row=quad*4+reg
#pragma unroll
    for (int ct = 0; ct < 2; ++ct) {
        const int col = c0 + cwl + ct * 16 + lr;
        const float bb = bias[col];
#pragma unroll
        for (int rt = 0; rt < 2; ++rt) {
#pragma unroll
            for (int reg = 0; reg < 4; ++reg) {
                const int r = r0 + rwl + rt * 16 + quad * 4 + reg;
                if (r < Q) {
                    float v = acc[rt][ct][reg] + bb;
                    if (mask && mask[r]) v = 0.f;
                    C[(size_t)r * NC + col] = v;
                }
            }
        }
    }
}

// ---------------------------------------------------------------------------
// Fused softmax + bilinear sampling + weighted accumulation (unchanged).
// One 64-lane wave per (q, m); 4 waves per block.
// ---------------------------------------------------------------------------
__global__ __launch_bounds__(256) void msda_k(
    const float* __restrict__ value, const float* __restrict__ off,
    const float* __restrict__ logits, const float* __restrict__ ref,
    float* __restrict__ out2, int Q)
{
    __shared__ int   sIdx[4][64];
    __shared__ float sWt[4][64];

    const int t = threadIdx.x;
    const int w = t >> 6;
    const int lane = t & 63;
    const int g = blockIdx.x * 4 + w;        // Q*8 divisible by 4
    const int q = g >> 3, m = g & 7;

    {
        const int p = lane >> 2;             // point 0..15
        const int c = lane & 3;              // corner 0..3
        const int l = p >> 2;                // level 0..3

        float logit = logits[(size_t)q * 128 + m * 16 + p];
        float mx = logit;
#pragma unroll
        for (int s = 4; s < 64; s <<= 1) mx = fmaxf(mx, __shfl_xor(mx, s, 64));
        const float e = __expf(logit - mx);
        float sum = e;
#pragma unroll
        for (int s = 4; s < 64; s <<= 1) sum += __shfl_xor(sum, s, 64);
        const float a = e / sum;

        const float ox = off[(size_t)q * 256 + m * 32 + p * 2 + 0];
        const float oy = off[(size_t)q * 256 + m * 32 + p * 2 + 1];
        const float rx = ref[(size_t)q * 8 + l * 2 + 0];
        const float ry = ref[(size_t)q * 8 + l * 2 + 1];

        const int Wc = (l == 0) ? 150 : (l == 1) ? 75 : (l == 2) ? 38 : 19;
        const int Hc = (l == 0) ? 100 : (l == 1) ? 50 : (l == 2) ? 25 : 13;
        const int s0 = (l == 0) ? 0 : (l == 1) ? 15000 : (l == 2) ? 18750 : 19700;
        const float fw = (float)Wc, fh = (float)Hc;

        float gx = 2.f * (rx + ox / fw) - 1.f;
        float gy = 2.f * (ry + oy / fh) - 1.f;
        gx = fminf(fmaxf(gx, -2.f), 2.f);
        gy = fminf(fmaxf(gy, -2.f), 2.f);
        const float x = (gx + 1.f) * (fw * 0.5f) - 0.5f;
        const float y = (gy + 1.f) * (fh * 0.5f) - 0.5f;
        const float x0f = floorf(x), y0f = floorf(y);
        const int x0 = (int)x0f, y0 = (int)y0f;
        const float wx1 = x - x0f, wy1 = y - y0f;

        const int cx = c & 1, cy = c >> 1;
        const int xi = x0 + cx, yi = y0 + cy;
        const float wx = cx ? wx1 : 1.f - wx1;
        const float wy = cy ? wy1 : 1.f - wy1;
        const bool valid = (xi >= 0) & (xi < Wc) & (yi >= 0) & (yi < Hc);
        const int xc = min(max(xi, 0), Wc - 1);
        const int yc = min(max(yi, 0), Hc - 1);

        sIdx[w][lane] = (s0 + yc * Wc + xc) * 256 + m * 32;
        sWt[w][lane] = valid ? a * wx * wy : 0.f;
    }
    __syncthreads();

    const int cg = lane >> 3;                // corner group 0..7
    const int ch = (lane & 7) * 4;           // channel quad base
    const float* vb = value + ch;

    float4 acc = {0.f, 0.f, 0.f, 0.f};
#pragma unroll
    for (int i = 0; i < 8; ++i) {
        const int k = i * 8 + cg;
        const float wt = sWt[w][k];
        const int idx = sIdx[w][k];
        const float4 v = *(const float4*)(vb + idx);
        acc.x += wt * v.x;
        acc.y += wt * v.y;
        acc.z += wt * v.z;
        acc.w += wt * v.w;
    }
#pragma unroll
    for (int s = 8; s < 64; s <<= 1) {
        acc.x += __shfl_xor(acc.x, s, 64);
        acc.y += __shfl_xor(acc.y, s, 64);
        acc.z += __shfl_xor(acc.z, s, 64);
        acc.w += __shfl_xor(acc.w, s, 64);
    }
    if (lane < 8)
        *(float4*)(out2 + (size_t)q * 256 + m * 32 + lane * 4) = acc;
}

// ---------------------------------------------------------------------------
extern "C" void kernel_launch(void* const* d_in, const int* in_sizes, int n_in,
                              void* d_out, int out_size, void* d_ws, size_t ws_size,
                              hipStream_t stream)
{
    const float* query = (const float*)d_in[0];                 // (Q, 256)
    const float* refpt = (const float*)d_in[1];                 // (Q, 4, 2)
    const float* inflat = (const float*)d_in[2];                // (Q, 256)
    const unsigned char* mask = (const unsigned char*)d_in[3];  // (Q,)
    const float* W_off = (const float*)d_in[4];                 // (256, 256)
    const float* b_off = (const float*)d_in[5];                 // (256,)
    const float* W_attn = (const float*)d_in[6];                // (256, 128)
    const float* b_attn = (const float*)d_in[7];                // (128,)
    const float* W_val = (const float*)d_in[8];                 // (256, 256)
    const float* b_val = (const float*)d_in[9];                 // (256,)
    const float* W_out = (const float*)d_in[10];                // (256, 256)
    const float* b_out = (const float*)d_in[11];                // (256,)
    float* out = (float*)d_out;

    const int Q = in_sizes[0] / DMODEL;  // 19947

    // Workspace: value | off | logits | out2 (fp32), then bf16 Wt arrays.
    float* value = (float*)d_ws;
    float* off   = value + (size_t)Q * 256;
    float* aw    = off   + (size_t)Q * 256;
    float* out2  = aw    + (size_t)Q * 128;
    unsigned short* WtVal  = (unsigned short*)(out2 + (size_t)Q * 256);
    unsigned short* WtOff  = WtVal  + 65536;
    unsigned short* WtAttn = WtOff  + 65536;   // 128*256
    unsigned short* WtOutH = WtAttn + 32768;
    unsigned short* WtOutL = WtOutH + 65536;

    // 0) transpose+convert weights
    wtrans_k<<<dim3(4, 4), 256, 0, stream>>>(W_val, WtVal, nullptr, 256);
    wtrans_k<<<dim3(4, 4), 256, 0, stream>>>(W_off, WtOff, nullptr, 256);
    wtrans_k<<<dim3(4, 2), 256, 0, stream>>>(W_attn, WtAttn, nullptr, 128);
    wtrans_k<<<dim3(4, 4), 256, 0, stream>>>(W_out, WtOutH, WtOutL, 256);

    const int rb = (Q + 63) / 64;   // 312

    // 1) value = inflat @ W_val + b_val (masked)
    gemm_mfma_k<256, false><<<dim3(rb, 4), 256, 0, stream>>>(
        inflat, WtVal, nullptr, b_val, value, Q, mask);
    // 2) off = query @ W_off + b_off
    gemm_mfma_k<256, false><<<dim3(rb, 4), 256, 0, stream>>>(
        query, WtOff, nullptr, b_off, off, Q, nullptr);
    // 3) logits = query @ W_attn + b_attn
    gemm_mfma_k<128, false><<<dim3(rb, 2), 256, 0, stream>>>(
        query, WtAttn, nullptr, b_attn, aw, Q, nullptr);
    // 4) fused softmax + sample + accumulate -> out2
    msda_k<<<(Q * 8) / 4, 256, 0, stream>>>(value, off, aw, refpt, out2, Q);
    // 5) out = out2 @ W_out + b_out  (hi/lo split for precision)
    gemm_mfma_k<256, true><<<dim3(rb, 4), 256, 0, stream>>>(
        out2, WtOutH, WtOutL, b_out, out, Q, nullptr);
}

// Round 4
// 216.346 us; speedup vs baseline: 2.2639x; 1.1582x over previous
//
#include <hip/hip_runtime.h>
#include <hip/hip_bf16.h>

// Deformable-DETR MSDeformAttn, Q=19947, D=256, M=8, L=4, P=4, DH=32.
// 4 dispatches: prep (weight transposes), fused input GEMMs (MFMA bf16),
// fused softmax+sampling, out-proj GEMM (MFMA bf16 hi/lo split).

#define DMODEL 256

typedef __attribute__((ext_vector_type(8))) short bf16x8;
typedef __attribute__((ext_vector_type(4))) float f32x4;

static __device__ inline unsigned short f2bf(float f) {
    unsigned int u = __builtin_bit_cast(unsigned int, f);
    u = (u + 0x7fffu + ((u >> 16) & 1u)) >> 16;   // RNE (finite inputs)
    return (unsigned short)u;
}
static __device__ inline float bf2f(unsigned short h) {
    return __builtin_bit_cast(float, (unsigned int)h << 16);
}
static __device__ inline float fast_rcp(float x) {
#if __has_builtin(__builtin_amdgcn_rcpf)
    return __builtin_amdgcn_rcpf(x);
#else
    return 1.f / x;
#endif
}

// ---------------------------------------------------------------------------
// prep_k: all weight transposes in ONE dispatch (56 blocks).
// W[k][c] fp32 -> Wt[c][k] bf16 (+ lo residual for W_out).
// blocks: [0,16) W_val | [16,32) W_off | [32,40) W_attn | [40,56) W_out split
// ---------------------------------------------------------------------------
__global__ __launch_bounds__(256) void prep_k(
    const float* __restrict__ Wv, const float* __restrict__ Wo,
    const float* __restrict__ Wa, const float* __restrict__ Wq,
    unsigned short* __restrict__ HV, unsigned short* __restrict__ HO,
    unsigned short* __restrict__ HA, unsigned short* __restrict__ HQh,
    unsigned short* __restrict__ HQl)
{
    __shared__ unsigned short tH[64][68];
    __shared__ unsigned short tL[64][68];

    int b = blockIdx.x;
    const float* W; unsigned short* H; unsigned short* L = nullptr; int NC;
    if (b < 16)      { W = Wv; H = HV; NC = 256; }
    else if (b < 32) { W = Wo; H = HO; NC = 256; b -= 16; }
    else if (b < 40) { W = Wa; H = HA; NC = 128; b -= 32; }
    else             { W = Wq; H = HQh; L = HQl; NC = 256; b -= 40; }
    const int k0 = (b & 3) * 64, c0 = (b >> 2) * 64;

    const int t = threadIdx.x;
    const int cl = t & 63;
#pragma unroll
    for (int i = 0; i < 16; ++i) {
        const int kl = (t >> 6) * 16 + i;
        const float v = W[(size_t)(k0 + kl) * NC + c0 + cl];
        const unsigned short h = f2bf(v);
        tH[cl][kl] = h;
        if (L) tL[cl][kl] = f2bf(v - bf2f(h));
    }
    __syncthreads();
    const int kl = t & 63;
#pragma unroll
    for (int i = 0; i < 16; ++i) {
        const int cl2 = (t >> 6) * 16 + i;
        H[(size_t)(c0 + cl2) * 256 + k0 + kl] = tH[cl2][kl];
        if (L) L[(size_t)(c0 + cl2) * 256 + k0 + kl] = tL[cl2][kl];
    }
}

// ---------------------------------------------------------------------------
// gemm_in_k: the three input GEMMs fused in one dispatch.
// grid (312, 5): y 0-1 value (A=inflat), y 2-3 off (A=query), y 4 logits.
// 64x128 tile / 256 threads; wave w owns 32x64 quadrant = 2x4 tiles of
// mfma_f32_16x16x32_bf16. Global loads for chunk k+1 overlap MFMA of chunk k.
// ---------------------------------------------------------------------------
__global__ __launch_bounds__(256) void gemm_in_k(
    const float* __restrict__ inflat, const float* __restrict__ query,
    const unsigned short* __restrict__ BtVal,
    const unsigned short* __restrict__ BtOff,
    const unsigned short* __restrict__ BtAttn,
    const float* __restrict__ b_val, const float* __restrict__ b_off,
    const float* __restrict__ b_attn,
    float* __restrict__ value, float* __restrict__ offo,
    float* __restrict__ logits, int Q, const unsigned char* __restrict__ mask)
{
    __shared__ unsigned short As[64][72];    // [row][k]
    __shared__ unsigned short Bs[128][72];   // [col][k]

    const int y = blockIdx.y;
    const float* A; const unsigned short* Bt; const float* bias;
    float* C; int NCout; const unsigned char* msk = nullptr; int c0;
    if (y < 2)      { A = inflat; Bt = BtVal;  bias = b_val;  C = value;  NCout = 256; c0 = y * 128; msk = mask; }
    else if (y < 4) { A = query;  Bt = BtOff;  bias = b_off;  C = offo;   NCout = 256; c0 = (y - 2) * 128; }
    else            { A = query;  Bt = BtAttn; bias = b_attn; C = logits; NCout = 128; c0 = 0; }

    const int t = threadIdx.x;
    const int w = t >> 6, lane = t & 63;
    const int lr = lane & 15, quad = lane >> 4;
    const int rwl = (w & 1) * 32, cwl = (w >> 1) * 64;
    const int r0 = blockIdx.x * 64;

    // staging assignments
    const int a_r = t >> 2, a_q = (t & 3) * 16;   // A: row, 16-float k-span
    const int b_c = t >> 1, b_k = (t & 1) * 32;   // B: col, 32-short k-span

    int ar = r0 + a_r; if (ar >= Q) ar = Q - 1;   // clamp: dup row, never stored
    const float* Arow = A + (size_t)ar * 256;
    const unsigned short* Brow = Bt + (size_t)(c0 + b_c) * 256;

    f32x4 acc[2][4];
#pragma unroll
    for (int i = 0; i < 2; ++i)
#pragma unroll
        for (int j = 0; j < 4; ++j) acc[i][j] = (f32x4){0.f, 0.f, 0.f, 0.f};

    float4 av[4]; bf16x8 bv[4];
    auto load_chunk = [&](int kc) {
#pragma unroll
        for (int j = 0; j < 4; ++j) av[j] = *(const float4*)(Arow + kc + a_q + j * 4);
#pragma unroll
        for (int j = 0; j < 4; ++j) bv[j] = *(const bf16x8*)(Brow + kc + b_k + j * 8);
    };
    auto stage_store = [&]() {
#pragma unroll
        for (int j = 0; j < 2; ++j) {
            const float fs[8] = {av[2*j].x, av[2*j].y, av[2*j].z, av[2*j].w,
                                 av[2*j+1].x, av[2*j+1].y, av[2*j+1].z, av[2*j+1].w};
            bf16x8 hv;
#pragma unroll
            for (int e = 0; e < 8; ++e) hv[e] = (short)f2bf(fs[e]);
            *(bf16x8*)&As[a_r][a_q + j * 8] = hv;
        }
#pragma unroll
        for (int j = 0; j < 4; ++j) *(bf16x8*)&Bs[b_c][b_k + j * 8] = bv[j];
    };

    load_chunk(0);
    stage_store();
    __syncthreads();

#pragma unroll
    for (int ch = 0; ch < 4; ++ch) {
        if (ch < 3) load_chunk((ch + 1) * 64);   // in flight during MFMA
#pragma unroll
        for (int ks = 0; ks < 2; ++ks) {
            const int kb = ks * 32 + quad * 8;
            bf16x8 af[2], bfr[4];
#pragma unroll
            for (int rt = 0; rt < 2; ++rt)
                af[rt] = *(const bf16x8*)&As[rwl + rt * 16 + lr][kb];
#pragma unroll
            for (int ct = 0; ct < 4; ++ct)
                bfr[ct] = *(const bf16x8*)&Bs[cwl + ct * 16 + lr][kb];
#pragma unroll
            for (int rt = 0; rt < 2; ++rt)
#pragma unroll
                for (int ct = 0; ct < 4; ++ct)
                    acc[rt][ct] = __builtin_amdgcn_mfma_f32_16x16x32_bf16(
                        af[rt], bfr[ct], acc[rt][ct], 0, 0, 0);
        }
        if (ch < 3) { __syncthreads(); stage_store(); __syncthreads(); }
    }

    // epilogue: C/D layout col=lane&15, row=quad*4+reg
#pragma unroll
    for (int ct = 0; ct < 4; ++ct) {
        const int col = c0 + cwl + ct * 16 + lr;
        const float bb = bias[col];
#pragma unroll
        for (int rt = 0; rt < 2; ++rt)
#pragma unroll
            for (int reg = 0; reg < 4; ++reg) {
                const int r = r0 + rwl + rt * 16 + quad * 4 + reg;
                if (r < Q) {
                    float v = acc[rt][ct][reg] + bb;
                    if (msk && msk[r]) v = 0.f;
                    C[(size_t)r * NCout + col] = v;
                }
            }
    }
}

// ---------------------------------------------------------------------------
// gemm_out_k: out = out2 @ W_out + b_out, bf16 hi/lo split (3 MFMAs/k-step).
// 64x64 tile / 256 threads, wave = 32x32 quadrant; prefetch pipeline.
// ---------------------------------------------------------------------------
__global__ __launch_bounds__(256) void gemm_out_k(
    const float* __restrict__ A, const unsigned short* __restrict__ BtH,
    const unsigned short* __restrict__ BtL, const float* __restrict__ bias,
    float* __restrict__ C, int Q)
{
    __shared__ unsigned short As[2][64][72];
    __shared__ unsigned short Bs[2][64][72];

    const int t = threadIdx.x;
    const int w = t >> 6, lane = t & 63;
    const int lr = lane & 15, quad = lane >> 4;
    const int rwl = (w & 1) * 32, cwl = (w >> 1) * 32;
    const int r0 = blockIdx.x * 64, c0 = blockIdx.y * 64;

    const int a_r = t >> 2, a_q = (t & 3) * 16;
    const int b_c = t >> 2, b_k = (t & 3) * 16;

    int ar = r0 + a_r; if (ar >= Q) ar = Q - 1;
    const float* Arow = A + (size_t)ar * 256;
    const unsigned short* BrowH = BtH + (size_t)(c0 + b_c) * 256;
    const unsigned short* BrowL = BtL + (size_t)(c0 + b_c) * 256;

    f32x4 acc[2][2];
#pragma unroll
    for (int i = 0; i < 2; ++i)
#pragma unroll
        for (int j = 0; j < 2; ++j) acc[i][j] = (f32x4){0.f, 0.f, 0.f, 0.f};

    float4 av[4]; bf16x8 bvH[2], bvL[2];
    auto load_chunk = [&](int kc) {
#pragma unroll
        for (int j = 0; j < 4; ++j) av[j] = *(const float4*)(Arow + kc + a_q + j * 4);
#pragma unroll
        for (int j = 0; j < 2; ++j) bvH[j] = *(const bf16x8*)(BrowH + kc + b_k + j * 8);
#pragma unroll
        for (int j = 0; j < 2; ++j) bvL[j] = *(const bf16x8*)(BrowL + kc + b_k + j * 8);
    };
    auto stage_store = [&]() {
#pragma unroll
        for (int j = 0; j < 2; ++j) {
            const float fs[8] = {av[2*j].x, av[2*j].y, av[2*j].z, av[2*j].w,
                                 av[2*j+1].x, av[2*j+1].y, av[2*j+1].z, av[2*j+1].w};
            bf16x8 hv, lv;
#pragma unroll
            for (int e = 0; e < 8; ++e) {
                const unsigned short h = f2bf(fs[e]);
                hv[e] = (short)h;
                lv[e] = (short)f2bf(fs[e] - bf2f(h));
            }
            *(bf16x8*)&As[0][a_r][a_q + j * 8] = hv;
            *(bf16x8*)&As[1][a_r][a_q + j * 8] = lv;
        }
#pragma unroll
        for (int j = 0; j < 2; ++j) *(bf16x8*)&Bs[0][b_c][b_k + j * 8] = bvH[j];
#pragma unroll
        for (int j = 0; j < 2; ++j) *(bf16x8*)&Bs[1][b_c][b_k + j * 8] = bvL[j];
    };

    load_chunk(0);
    stage_store();
    __syncthreads();

#pragma unroll
    for (int ch = 0; ch < 4; ++ch) {
        if (ch < 3) load_chunk((ch + 1) * 64);
#pragma unroll
        for (int ks = 0; ks < 2; ++ks) {
            const int kb = ks * 32 + quad * 8;
            bf16x8 ah[2], al[2], bh[2], bl[2];
#pragma unroll
            for (int rt = 0; rt < 2; ++rt) {
                ah[rt] = *(const bf16x8*)&As[0][rwl + rt * 16 + lr][kb];
                al[rt] = *(const bf16x8*)&As[1][rwl + rt * 16 + lr][kb];
            }
#pragma unroll
            for (int ct = 0; ct < 2; ++ct) {
                bh[ct] = *(const bf16x8*)&Bs[0][cwl + ct * 16 + lr][kb];
                bl[ct] = *(const bf16x8*)&Bs[1][cwl + ct * 16 + lr][kb];
            }
#pragma unroll
            for (int rt = 0; rt < 2; ++rt)
#pragma unroll
                for (int ct = 0; ct < 2; ++ct) {
                    acc[rt][ct] = __builtin_amdgcn_mfma_f32_16x16x32_bf16(
                        ah[rt], bh[ct], acc[rt][ct], 0, 0, 0);
                    acc[rt][ct] = __builtin_amdgcn_mfma_f32_16x16x32_bf16(
                        al[rt], bh[ct], acc[rt][ct], 0, 0, 0);
                    acc[rt][ct] = __builtin_amdgcn_mfma_f32_16x16x32_bf16(
                        ah[rt], bl[ct], acc[rt][ct], 0, 0, 0);
                }
        }
        if (ch < 3) { __syncthreads(); stage_store(); __syncthreads(); }
    }

#pragma unroll
    for (int ct = 0; ct < 2; ++ct) {
        const int col = c0 + cwl + ct * 16 + lr;
        const float bb = bias[col];
#pragma unroll
        for (int rt = 0; rt < 2; ++rt)
#pragma unroll
            for (int reg = 0; reg < 4; ++reg) {
                const int r = r0 + rwl + rt * 16 + quad * 4 + reg;
                if (r < Q) C[(size_t)r * 256 + col] = acc[rt][ct][reg] + bb;
            }
    }
}

// ---------------------------------------------------------------------------
// msda_k: fused softmax + bilinear sampling + weighted accumulation.
// One 64-lane wave per (q, m); 4 waves/block.
// Phase 1 collapse: x = rx*W + ox - 0.5 exactly reproduces the reference's
// clip/affine chain (clip at +-2 never binds: |ox|<=4.5 -> |gx|<=1.5; and in
// all |gx|>2 regimes every corner is invalid -> 0 either way).
// ---------------------------------------------------------------------------
__global__ __launch_bounds__(256) void msda_k(
    const float* __restrict__ value, const float* __restrict__ off,
    const float* __restrict__ logits, const float* __restrict__ ref,
    float* __restrict__ out2, int Q)
{
    __shared__ int   sIdx[4][64];
    __shared__ float sWt[4][64];

    const int t = threadIdx.x;
    const int w = t >> 6;
    const int lane = t & 63;
    const int g = blockIdx.x * 4 + w;        // Q*8 divisible by 4
    const int q = g >> 3, m = g & 7;

    {
        const int p = lane >> 2;             // point 0..15
        const int c = lane & 3;              // corner 0..3
        const int l = p >> 2;                // level 0..3

        const float logit = logits[(size_t)q * 128 + m * 16 + p];
        float mx = logit;
#pragma unroll
        for (int s = 4; s < 64; s <<= 1) mx = fmaxf(mx, __shfl_xor(mx, s, 64));
        const float e = __expf(logit - mx);
        float sum = e;
#pragma unroll
        for (int s = 4; s < 64; s <<= 1) sum += __shfl_xor(sum, s, 64);
        const float a = e * fast_rcp(sum);

        const float2 oxy = *(const float2*)(off + (size_t)q * 256 + m * 32 + p * 2);
        const float2 rxy = *(const float2*)(ref + (size_t)q * 8 + l * 2);

        const int Wc = (l == 0) ? 150 : (l == 1) ? 75 : (l == 2) ? 38 : 19;
        const int Hc = (l == 0) ? 100 : (l == 1) ? 50 : (l == 2) ? 25 : 13;
        const int s0 = (l == 0) ? 0 : (l == 1) ? 15000 : (l == 2) ? 18750 : 19700;

        const float x = fmaf(rxy.x, (float)Wc, oxy.x) - 0.5f;
        const float y = fmaf(rxy.y, (float)Hc, oxy.y) - 0.5f;
        const float x0f = floorf(x), y0f = floorf(y);
        const float wx1 = x - x0f, wy1 = y - y0f;
        const int x0 = (int)x0f, y0 = (int)y0f;

        const int cx = c & 1, cy = c >> 1;
        const int xi = x0 + cx, yi = y0 + cy;
        const bool valid = ((unsigned)xi < (unsigned)Wc) & ((unsigned)yi < (unsigned)Hc);
        const float wx = cx ? wx1 : 1.f - wx1;
        const float wy = cy ? wy1 : 1.f - wy1;
        const int xc = min(max(xi, 0), Wc - 1);
        const int yc = min(max(yi, 0), Hc - 1);

        sIdx[w][lane] = (s0 + yc * Wc + xc) * 256 + m * 32;
        sWt[w][lane] = valid ? a * wx * wy : 0.f;
    }
    __syncthreads();

    // phase 2: batch all 8 gathers (independent, in flight together)
    const int cg = lane >> 3;                // corner group 0..7
    const int chq = (lane & 7) * 4;          // channel quad
    const float* vb = value + chq;

    float wtv[8]; int idxv[8];
#pragma unroll
    for (int i = 0; i < 8; ++i) {
        wtv[i] = sWt[w][i * 8 + cg];
        idxv[i] = sIdx[w][i * 8 + cg];
    }
    float4 vv[8];
#pragma unroll
    for (int i = 0; i < 8; ++i) vv[i] = *(const float4*)(vb + idxv[i]);

    float4 acc = {0.f, 0.f, 0.f, 0.f};
#pragma unroll
    for (int i = 0; i < 8; ++i) {
        acc.x += wtv[i] * vv[i].x;
        acc.y += wtv[i] * vv[i].y;
        acc.z += wtv[i] * vv[i].z;
        acc.w += wtv[i] * vv[i].w;
    }
#pragma unroll
    for (int s = 8; s < 64; s <<= 1) {
        acc.x += __shfl_xor(acc.x, s, 64);
        acc.y += __shfl_xor(acc.y, s, 64);
        acc.z += __shfl_xor(acc.z, s, 64);
        acc.w += __shfl_xor(acc.w, s, 64);
    }
    if (lane < 8)
        *(float4*)(out2 + (size_t)q * 256 + m * 32 + lane * 4) = acc;
}

// ---------------------------------------------------------------------------
extern "C" void kernel_launch(void* const* d_in, const int* in_sizes, int n_in,
                              void* d_out, int out_size, void* d_ws, size_t ws_size,
                              hipStream_t stream)
{
    const float* query = (const float*)d_in[0];                 // (Q, 256)
    const float* refpt = (const float*)d_in[1];                 // (Q, 4, 2)
    const float* inflat = (const float*)d_in[2];                // (Q, 256)
    const unsigned char* mask = (const unsigned char*)d_in[3];  // (Q,)
    const float* W_off = (const float*)d_in[4];                 // (256, 256)
    const float* b_off = (const float*)d_in[5];                 // (256,)
    const float* W_attn = (const float*)d_in[6];                // (256, 128)
    const float* b_attn = (const float*)d_in[7];                // (128,)
    const float* W_val = (const float*)d_in[8];                 // (256, 256)
    const float* b_val = (const float*)d_in[9];                 // (256,)
    const float* W_out = (const float*)d_in[10];                // (256, 256)
    const float* b_out = (const float*)d_in[11];                // (256,)
    float* out = (float*)d_out;

    const int Q = in_sizes[0] / DMODEL;  // 19947

    // Workspace: value | off | logits | out2 (fp32), then bf16 Wt arrays.
    float* value = (float*)d_ws;
    float* offo  = value + (size_t)Q * 256;
    float* aw    = offo  + (size_t)Q * 256;
    float* out2  = aw    + (size_t)Q * 128;
    unsigned short* WtVal  = (unsigned short*)(out2 + (size_t)Q * 256);
    unsigned short* WtOff  = WtVal  + 65536;
    unsigned short* WtAttn = WtOff  + 65536;   // 128*256
    unsigned short* WtOutH = WtAttn + 32768;
    unsigned short* WtOutL = WtOutH + 65536;

    const int rb = (Q + 63) / 64;   // 312

    // 1) all weight transposes, one dispatch
    prep_k<<<56, 256, 0, stream>>>(W_val, W_off, W_attn, W_out,
                                   WtVal, WtOff, WtAttn, WtOutH, WtOutL);
    // 2) value / off / logits GEMMs, one dispatch
    gemm_in_k<<<dim3(rb, 5), 256, 0, stream>>>(
        inflat, query, WtVal, WtOff, WtAttn, b_val, b_off, b_attn,
        value, offo, aw, Q, mask);
    // 3) fused softmax + sample + accumulate -> out2
    msda_k<<<(Q * 8) / 4, 256, 0, stream>>>(value, offo, aw, refpt, out2, Q);
    // 4) out = out2 @ W_out + b_out (hi/lo split)
    gemm_out_k<<<dim3(rb, 4), 256, 0, stream>>>(out2, WtOutH, WtOutL, b_out, out, Q);
}

// Round 5
// 213.004 us; speedup vs baseline: 2.2994x; 1.0157x over previous
//
#include <hip/hip_runtime.h>
#include <hip/hip_bf16.h>

// Deformable-DETR MSDeformAttn, Q=19947, D=256, M=8, L=4, P=4, DH=32.
// 4 dispatches: prep (weight transposes + A fp32->bf16), fused input GEMMs
// (MFMA bf16, value stored bf16), fused softmax+sampling (bf16 gathers,
// out2 written bf16 hi/lo), out-proj GEMM (MFMA bf16 hi/lo split).

#define DMODEL 256

typedef __attribute__((ext_vector_type(8))) short bf16x8;
typedef __attribute__((ext_vector_type(4))) float f32x4;

static __device__ inline unsigned short f2bf(float f) {
    unsigned int u = __builtin_bit_cast(unsigned int, f);
    u = (u + 0x7fffu + ((u >> 16) & 1u)) >> 16;   // RNE (finite inputs)
    return (unsigned short)u;
}
static __device__ inline float bf2f(unsigned short h) {
    return __builtin_bit_cast(float, (unsigned int)h << 16);
}
static __device__ inline float fast_rcp(float x) {
#if __has_builtin(__builtin_amdgcn_rcpf)
    return __builtin_amdgcn_rcpf(x);
#else
    return 1.f / x;
#endif
}

// ---------------------------------------------------------------------------
// prep_k: weight transposes (blocks 0..55) + inflat/query fp32->bf16 convert
// (blocks 56..). W[k][c] fp32 -> Wt[c][k] bf16 (+ lo residual for W_out).
// ---------------------------------------------------------------------------
__global__ __launch_bounds__(256) void prep_k(
    const float* __restrict__ Wv, const float* __restrict__ Wo,
    const float* __restrict__ Wa, const float* __restrict__ Wq,
    unsigned short* __restrict__ HV, unsigned short* __restrict__ HO,
    unsigned short* __restrict__ HA, unsigned short* __restrict__ HQh,
    unsigned short* __restrict__ HQl,
    const float* __restrict__ inflat, const float* __restrict__ query,
    unsigned short* __restrict__ inflat_bf, unsigned short* __restrict__ query_bf,
    int QD)
{
    int b = blockIdx.x;
    if (b >= 56) {
        // A conversion: 8 consecutive floats per thread.
        const int f = ((b - 56) * 256 + (int)threadIdx.x) * 8;
        if (f < 2 * QD) {
            const float* src; unsigned short* dst; int i;
            if (f < QD) { src = inflat; dst = inflat_bf; i = f; }
            else        { src = query;  dst = query_bf;  i = f - QD; }
            const float4 v0 = *(const float4*)(src + i);
            const float4 v1 = *(const float4*)(src + i + 4);
            bf16x8 h;
            h[0] = (short)f2bf(v0.x); h[1] = (short)f2bf(v0.y);
            h[2] = (short)f2bf(v0.z); h[3] = (short)f2bf(v0.w);
            h[4] = (short)f2bf(v1.x); h[5] = (short)f2bf(v1.y);
            h[6] = (short)f2bf(v1.z); h[7] = (short)f2bf(v1.w);
            *(bf16x8*)(dst + i) = h;
        }
        return;
    }

    __shared__ unsigned short tH[64][68];
    __shared__ unsigned short tL[64][68];

    const float* W; unsigned short* H; unsigned short* L = nullptr; int NC;
    if (b < 16)      { W = Wv; H = HV; NC = 256; }
    else if (b < 32) { W = Wo; H = HO; NC = 256; b -= 16; }
    else if (b < 40) { W = Wa; H = HA; NC = 128; b -= 32; }
    else             { W = Wq; H = HQh; L = HQl; NC = 256; b -= 40; }
    const int k0 = (b & 3) * 64, c0 = (b >> 2) * 64;

    const int t = threadIdx.x;
    const int cl = t & 63;
#pragma unroll
    for (int i = 0; i < 16; ++i) {
        const int kl = (t >> 6) * 16 + i;
        const float v = W[(size_t)(k0 + kl) * NC + c0 + cl];
        const unsigned short h = f2bf(v);
        tH[cl][kl] = h;
        if (L) tL[cl][kl] = f2bf(v - bf2f(h));
    }
    __syncthreads();
    const int kl = t & 63;
#pragma unroll
    for (int i = 0; i < 16; ++i) {
        const int cl2 = (t >> 6) * 16 + i;
        H[(size_t)(c0 + cl2) * 256 + k0 + kl] = tH[cl2][kl];
        if (L) L[(size_t)(c0 + cl2) * 256 + k0 + kl] = tL[cl2][kl];
    }
}

// ---------------------------------------------------------------------------
// gemm_in_k: the three input GEMMs fused; A pre-converted bf16 (pure-copy
// staging, no conversions in the hot loop). grid (312, 5):
// y 0-1 value (A=inflat, C stored bf16), y 2-3 off, y 4 logits.
// 64x128 tile / 256 threads; wave = 32x64 quadrant = 2x4 MFMA tiles.
// ---------------------------------------------------------------------------
__global__ __launch_bounds__(256) void gemm_in_k(
    const unsigned short* __restrict__ inflat_bf,
    const unsigned short* __restrict__ query_bf,
    const unsigned short* __restrict__ BtVal,
    const unsigned short* __restrict__ BtOff,
    const unsigned short* __restrict__ BtAttn,
    const float* __restrict__ b_val, const float* __restrict__ b_off,
    const float* __restrict__ b_attn,
    unsigned short* __restrict__ value_bf, float* __restrict__ offo,
    float* __restrict__ logits, int Q, const unsigned char* __restrict__ mask)
{
    __shared__ unsigned short As[64][72];    // [row][k]
    __shared__ unsigned short Bs[128][72];   // [col][k]

    const int y = blockIdx.y;
    const unsigned short* A; const unsigned short* Bt; const float* bias; int c0;
    if (y < 2)      { A = inflat_bf; Bt = BtVal;  bias = b_val;  c0 = y * 128; }
    else if (y < 4) { A = query_bf;  Bt = BtOff;  bias = b_off;  c0 = (y - 2) * 128; }
    else            { A = query_bf;  Bt = BtAttn; bias = b_attn; c0 = 0; }

    const int t = threadIdx.x;
    const int w = t >> 6, lane = t & 63;
    const int lr = lane & 15, quad = lane >> 4;
    const int rwl = (w & 1) * 32, cwl = (w >> 1) * 64;
    const int r0 = blockIdx.x * 64;

    const int a_r = t >> 2, a_q = (t & 3) * 16;   // A: row, 16-short k-span
    const int b_c = t >> 1, b_k = (t & 1) * 32;   // B: col, 32-short k-span

    int ar = r0 + a_r; if (ar >= Q) ar = Q - 1;   // clamp: dup row, never stored
    const unsigned short* Arow = A + (size_t)ar * 256;
    const unsigned short* Brow = Bt + (size_t)(c0 + b_c) * 256;

    f32x4 acc[2][4];
#pragma unroll
    for (int i = 0; i < 2; ++i)
#pragma unroll
        for (int j = 0; j < 4; ++j) acc[i][j] = (f32x4){0.f, 0.f, 0.f, 0.f};

    bf16x8 av[2], bv[4];
    auto load_chunk = [&](int kc) {
#pragma unroll
        for (int j = 0; j < 2; ++j) av[j] = *(const bf16x8*)(Arow + kc + a_q + j * 8);
#pragma unroll
        for (int j = 0; j < 4; ++j) bv[j] = *(const bf16x8*)(Brow + kc + b_k + j * 8);
    };
    auto stage_store = [&]() {
#pragma unroll
        for (int j = 0; j < 2; ++j) *(bf16x8*)&As[a_r][a_q + j * 8] = av[j];
#pragma unroll
        for (int j = 0; j < 4; ++j) *(bf16x8*)&Bs[b_c][b_k + j * 8] = bv[j];
    };

    load_chunk(0);
    stage_store();
    __syncthreads();

#pragma unroll
    for (int ch = 0; ch < 4; ++ch) {
        if (ch < 3) load_chunk((ch + 1) * 64);   // in flight during MFMA
#pragma unroll
        for (int ks = 0; ks < 2; ++ks) {
            const int kb = ks * 32 + quad * 8;
            bf16x8 af[2], bfr[4];
#pragma unroll
            for (int rt = 0; rt < 2; ++rt)
                af[rt] = *(const bf16x8*)&As[rwl + rt * 16 + lr][kb];
#pragma unroll
            for (int ct = 0; ct < 4; ++ct)
                bfr[ct] = *(const bf16x8*)&Bs[cwl + ct * 16 + lr][kb];
#pragma unroll
            for (int rt = 0; rt < 2; ++rt)
#pragma unroll
                for (int ct = 0; ct < 4; ++ct)
                    acc[rt][ct] = __builtin_amdgcn_mfma_f32_16x16x32_bf16(
                        af[rt], bfr[ct], acc[rt][ct], 0, 0, 0);
        }
        if (ch < 3) { __syncthreads(); stage_store(); __syncthreads(); }
    }

    // epilogue: C/D layout col=lane&15, row=quad*4+reg
#pragma unroll
    for (int ct = 0; ct < 4; ++ct) {
        const int col = c0 + cwl + ct * 16 + lr;
        const float bb = bias[col];
#pragma unroll
        for (int rt = 0; rt < 2; ++rt)
#pragma unroll
            for (int reg = 0; reg < 4; ++reg) {
                const int r = r0 + rwl + rt * 16 + quad * 4 + reg;
                if (r < Q) {
                    float v = acc[rt][ct][reg] + bb;
                    if (y < 2) {
                        if (mask && mask[r]) v = 0.f;
                        value_bf[(size_t)r * 256 + col] = f2bf(v);
                    } else if (y < 4) {
                        offo[(size_t)r * 256 + col] = v;
                    } else {
                        logits[(size_t)r * 128 + col] = v;
                    }
                }
            }
    }
}

// ---------------------------------------------------------------------------
// msda_k: fused softmax + bilinear sampling + weighted accumulation.
// One 64-lane wave per (q, m); 4 waves/block; NO LDS, no barrier.
// Phase 1: lane = point*4+corner computes (idx, weight); softmax via shuffles.
// Phase 2: lane = corner_group*8 + channel_quad; wt/idx via dynamic __shfl;
//          8 independent 8B bf16 gathers in flight; butterfly reduce; write
//          out2 as bf16 hi/lo pair (feeds the split out-proj GEMM).
// Affine collapse x = rx*W + ox - 0.5 is exact (clip at +-2 never binds:
// |ox|<=4.5 -> |gx|<=1.5; all out-of-range corners are zeroed by validity).
// ---------------------------------------------------------------------------
__global__ __launch_bounds__(256) void msda_k(
    const unsigned short* __restrict__ value, const float* __restrict__ off,
    const float* __restrict__ logits, const float* __restrict__ ref,
    unsigned short* __restrict__ out2h, unsigned short* __restrict__ out2l,
    int Q)
{
    const int t = threadIdx.x;
    const int w = t >> 6;
    const int lane = t & 63;
    const int g = blockIdx.x * 4 + w;        // Q*8 divisible by 4
    const int q = g >> 3, m = g & 7;

    // ---- phase 1: one corner per lane ----
    const int p = lane >> 2;             // point 0..15
    const int c = lane & 3;              // corner 0..3
    const int l = p >> 2;                // level 0..3

    const float logit = logits[(size_t)q * 128 + m * 16 + p];
    float mx = logit;
#pragma unroll
    for (int s = 4; s < 64; s <<= 1) mx = fmaxf(mx, __shfl_xor(mx, s, 64));
    const float e = __expf(logit - mx);
    float sum = e;
#pragma unroll
    for (int s = 4; s < 64; s <<= 1) sum += __shfl_xor(sum, s, 64);
    const float a = e * fast_rcp(sum);

    const float2 oxy = *(const float2*)(off + (size_t)q * 256 + m * 32 + p * 2);
    const float2 rxy = *(const float2*)(ref + (size_t)q * 8 + l * 2);

    const int Wc = (l == 0) ? 150 : (l == 1) ? 75 : (l == 2) ? 38 : 19;
    const int Hc = (l == 0) ? 100 : (l == 1) ? 50 : (l == 2) ? 25 : 13;
    const int s0 = (l == 0) ? 0 : (l == 1) ? 15000 : (l == 2) ? 18750 : 19700;

    const float x = fmaf(rxy.x, (float)Wc, oxy.x) - 0.5f;
    const float y = fmaf(rxy.y, (float)Hc, oxy.y) - 0.5f;
    const float x0f = floorf(x), y0f = floorf(y);
    const float wx1 = x - x0f, wy1 = y - y0f;
    const int x0 = (int)x0f, y0 = (int)y0f;

    const int cx = c & 1, cy = c >> 1;
    const int xi = x0 + cx, yi = y0 + cy;
    const bool valid = ((unsigned)xi < (unsigned)Wc) & ((unsigned)yi < (unsigned)Hc);
    const float wx = cx ? wx1 : 1.f - wx1;
    const float wy = cy ? wy1 : 1.f - wy1;
    const int xc = min(max(xi, 0), Wc - 1);
    const int yc = min(max(yi, 0), Hc - 1);

    const int myIdx = (s0 + yc * Wc + xc) * 256 + m * 32;   // short-elem index
    const float myWt = valid ? a * wx * wy : 0.f;

    // ---- phase 2: gather + accumulate (no barrier; shfl handoff) ----
    const int cg = lane >> 3;                // corner group 0..7
    const int chq = (lane & 7) * 4;          // channel quad (shorts)

    float wtv[8]; int idxv[8];
#pragma unroll
    for (int i = 0; i < 8; ++i) {
        const int k = i * 8 + cg;
        wtv[i]  = __shfl(myWt, k, 64);
        idxv[i] = __shfl(myIdx, k, 64);
    }
    ushort4 hv[8];
#pragma unroll
    for (int i = 0; i < 8; ++i)
        hv[i] = *(const ushort4*)(value + idxv[i] + chq);

    float4 acc = {0.f, 0.f, 0.f, 0.f};
#pragma unroll
    for (int i = 0; i < 8; ++i) {
        acc.x += wtv[i] * bf2f(hv[i].x);
        acc.y += wtv[i] * bf2f(hv[i].y);
        acc.z += wtv[i] * bf2f(hv[i].z);
        acc.w += wtv[i] * bf2f(hv[i].w);
    }
#pragma unroll
    for (int s = 8; s < 64; s <<= 1) {
        acc.x += __shfl_xor(acc.x, s, 64);
        acc.y += __shfl_xor(acc.y, s, 64);
        acc.z += __shfl_xor(acc.z, s, 64);
        acc.w += __shfl_xor(acc.w, s, 64);
    }
    if (lane < 8) {
        const float av[4] = {acc.x, acc.y, acc.z, acc.w};
        ushort4 hi, lo;
        unsigned short* hp = (unsigned short*)&hi;
        unsigned short* lp = (unsigned short*)&lo;
#pragma unroll
        for (int e2 = 0; e2 < 4; ++e2) {
            const unsigned short h = f2bf(av[e2]);
            hp[e2] = h;
            lp[e2] = f2bf(av[e2] - bf2f(h));
        }
        const size_t o = (size_t)q * 256 + m * 32 + lane * 4;
        *(ushort4*)(out2h + o) = hi;
        *(ushort4*)(out2l + o) = lo;
    }
}

// ---------------------------------------------------------------------------
// gemm_out_k: out = out2 @ W_out + b_out; A given as bf16 hi/lo pair,
// B pre-transposed bf16 hi/lo. D = Ah*Bh + Al*Bh + Ah*Bl (3 MFMAs/k-step).
// 64x64 tile / 256 threads, wave = 32x32 quadrant; pure-copy staging.
// ---------------------------------------------------------------------------
__global__ __launch_bounds__(256) void gemm_out_k(
    const unsigned short* __restrict__ AH, const unsigned short* __restrict__ AL,
    const unsigned short* __restrict__ BtH, const unsigned short* __restrict__ BtL,
    const float* __restrict__ bias, float* __restrict__ C, int Q)
{
    __shared__ unsigned short As[2][64][72];
    __shared__ unsigned short Bs[2][64][72];

    const int t = threadIdx.x;
    const int w = t >> 6, lane = t & 63;
    const int lr = lane & 15, quad = lane >> 4;
    const int rwl = (w & 1) * 32, cwl = (w >> 1) * 32;
    const int r0 = blockIdx.x * 64, c0 = blockIdx.y * 64;

    const int a_r = t >> 2, a_k = (t & 3) * 16;
    const int b_c = t >> 2, b_k = (t & 3) * 16;

    int ar = r0 + a_r; if (ar >= Q) ar = Q - 1;
    const unsigned short* ArowH = AH + (size_t)ar * 256;
    const unsigned short* ArowL = AL + (size_t)ar * 256;
    const unsigned short* BrowH = BtH + (size_t)(c0 + b_c) * 256;
    const unsigned short* BrowL = BtL + (size_t)(c0 + b_c) * 256;

    f32x4 acc[2][2];
#pragma unroll
    for (int i = 0; i < 2; ++i)
#pragma unroll
        for (int j = 0; j < 2; ++j) acc[i][j] = (f32x4){0.f, 0.f, 0.f, 0.f};

    bf16x8 avh[2], avl[2], bvh[2], bvl[2];
    auto load_chunk = [&](int kc) {
#pragma unroll
        for (int j = 0; j < 2; ++j) {
            avh[j] = *(const bf16x8*)(ArowH + kc + a_k + j * 8);
            avl[j] = *(const bf16x8*)(ArowL + kc + a_k + j * 8);
            bvh[j] = *(const bf16x8*)(BrowH + kc + b_k + j * 8);
            bvl[j] = *(const bf16x8*)(BrowL + kc + b_k + j * 8);
        }
    };
    auto stage_store = [&]() {
#pragma unroll
        for (int j = 0; j < 2; ++j) {
            *(bf16x8*)&As[0][a_r][a_k + j * 8] = avh[j];
            *(bf16x8*)&As[1][a_r][a_k + j * 8] = avl[j];
            *(bf16x8*)&Bs[0][b_c][b_k + j * 8] = bvh[j];
            *(bf16x8*)&Bs[1][b_c][b_k + j * 8] = bvl[j];
        }
    };

    load_chunk(0);
    stage_store();
    __syncthreads();

#pragma unroll
    for (int ch = 0; ch < 4; ++ch) {
        if (ch < 3) load_chunk((ch + 1) * 64);
#pragma unroll
        for (int ks = 0; ks < 2; ++ks) {
            const int kb = ks * 32 + quad * 8;
            bf16x8 ah[2], al[2], bh[2], bl[2];
#pragma unroll
            for (int rt = 0; rt < 2; ++rt) {
                ah[rt] = *(const bf16x8*)&As[0][rwl + rt * 16 + lr][kb];
                al[rt] = *(const bf16x8*)&As[1][rwl + rt * 16 + lr][kb];
            }
#pragma unroll
            for (int ct = 0; ct < 2; ++ct) {
                bh[ct] = *(const bf16x8*)&Bs[0][cwl + ct * 16 + lr][kb];
                bl[ct] = *(const bf16x8*)&Bs[1][cwl + ct * 16 + lr][kb];
            }
#pragma unroll
            for (int rt = 0; rt < 2; ++rt)
#pragma unroll
                for (int ct = 0; ct < 2; ++ct) {
                    acc[rt][ct] = __builtin_amdgcn_mfma_f32_16x16x32_bf16(
                        ah[rt], bh[ct], acc[rt][ct], 0, 0, 0);
                    acc[rt][ct] = __builtin_amdgcn_mfma_f32_16x16x32_bf16(
                        al[rt], bh[ct], acc[rt][ct], 0, 0, 0);
                    acc[rt][ct] = __builtin_amdgcn_mfma_f32_16x16x32_bf16(
                        ah[rt], bl[ct], acc[rt][ct], 0, 0, 0);
                }
        }
        if (ch < 3) { __syncthreads(); stage_store(); __syncthreads(); }
    }

#pragma unroll
    for (int ct = 0; ct < 2; ++ct) {
        const int col = c0 + cwl + ct * 16 + lr;
        const float bb = bias[col];
#pragma unroll
        for (int rt = 0; rt < 2; ++rt)
#pragma unroll
            for (int reg = 0; reg < 4; ++reg) {
                const int r = r0 + rwl + rt * 16 + quad * 4 + reg;
                if (r < Q) C[(size_t)r * 256 + col] = acc[rt][ct][reg] + bb;
            }
    }
}

// ---------------------------------------------------------------------------
extern "C" void kernel_launch(void* const* d_in, const int* in_sizes, int n_in,
                              void* d_out, int out_size, void* d_ws, size_t ws_size,
                              hipStream_t stream)
{
    const float* query = (const float*)d_in[0];                 // (Q, 256)
    const float* refpt = (const float*)d_in[1];                 // (Q, 4, 2)
    const float* inflat = (const float*)d_in[2];                // (Q, 256)
    const unsigned char* mask = (const unsigned char*)d_in[3];  // (Q,)
    const float* W_off = (const float*)d_in[4];                 // (256, 256)
    const float* b_off = (const float*)d_in[5];                 // (256,)
    const float* W_attn = (const float*)d_in[6];                // (256, 128)
    const float* b_attn = (const float*)d_in[7];                // (128,)
    const float* W_val = (const float*)d_in[8];                 // (256, 256)
    const float* b_val = (const float*)d_in[9];                 // (256,)
    const float* W_out = (const float*)d_in[10];                // (256, 256)
    const float* b_out = (const float*)d_in[11];                // (256,)
    float* out = (float*)d_out;

    const int Q = in_sizes[0] / DMODEL;  // 19947
    const int QD = Q * DMODEL;

    // Workspace layout
    unsigned short* value_bf  = (unsigned short*)d_ws;                    // Q*256
    float*          offo      = (float*)(value_bf + (size_t)QD);          // Q*256
    float*          logits    = offo + (size_t)QD;                        // Q*128
    unsigned short* out2h     = (unsigned short*)(logits + (size_t)Q * 128);
    unsigned short* out2l     = out2h + (size_t)QD;
    unsigned short* inflat_bf = out2l + (size_t)QD;
    unsigned short* query_bf  = inflat_bf + (size_t)QD;
    unsigned short* WtVal     = query_bf + (size_t)QD;
    unsigned short* WtOff     = WtVal  + 65536;
    unsigned short* WtAttn    = WtOff  + 65536;   // 128*256
    unsigned short* WtOutH    = WtAttn + 32768;
    unsigned short* WtOutL    = WtOutH + 65536;

    const int rb = (Q + 63) / 64;                      // 312
    const int na = (2 * QD + 2047) / 2048;             // A-convert blocks

    // 1) weight transposes + A bf16 conversion, one dispatch
    prep_k<<<56 + na, 256, 0, stream>>>(W_val, W_off, W_attn, W_out,
                                        WtVal, WtOff, WtAttn, WtOutH, WtOutL,
                                        inflat, query, inflat_bf, query_bf, QD);
    // 2) value(bf16) / off / logits GEMMs, one dispatch
    gemm_in_k<<<dim3(rb, 5), 256, 0, stream>>>(
        inflat_bf, query_bf, WtVal, WtOff, WtAttn, b_val, b_off, b_attn,
        value_bf, offo, logits, Q, mask);
    // 3) fused softmax + sample + accumulate -> out2 (bf16 hi/lo)
    msda_k<<<(Q * 8) / 4, 256, 0, stream>>>(value_bf, offo, logits, refpt,
                                            out2h, out2l, Q);
    // 4) out = out2 @ W_out + b_out (hi/lo split)
    gemm_out_k<<<dim3(rb, 4), 256, 0, stream>>>(out2h, out2l, WtOutH, WtOutL,
                                                b_out, out, Q);
}